// Round 1
// baseline (80.547 us; speedup 1.0000x reference)
//
#include <hip/hip_runtime.h>
#include <math.h>

#define WINDOW 50
#define BPT 256          // windows per block
#define HID 32           // hidden
#define H2X (2*HID)      // 64

__global__ __launch_bounds__(256) void nsg_kernel(
    const float* __restrict__ x,
    const float* __restrict__ w1, const float* __restrict__ b1,
    const float* __restrict__ w2, const float* __restrict__ b2,
    const float* __restrict__ w3, const float* __restrict__ b3,
    float* __restrict__ out, int B, int N, int M, int tiles)
{
    __shared__ float s_x[BPT + WINDOW];   // 306
    __shared__ float s_w1[4 * H2X];       // 256
    __shared__ float s_b1[H2X];           // 64
    __shared__ float s_w2[H2X * HID];     // 2048
    __shared__ float s_b2[HID];           // 32
    __shared__ float s_w3[HID * 2];       // 64
    __shared__ float s_b3[2];

    const int tid  = threadIdx.x;
    const int tile = blockIdx.x % tiles;
    const int row  = blockIdx.x / tiles;
    const int m0   = tile * BPT;

    // stage weights
    s_w1[tid] = w1[tid];                         // 256
    if (tid < H2X) s_b1[tid] = b1[tid];
    #pragma unroll
    for (int i = 0; i < 8; ++i) s_w2[tid + i * 256] = w2[tid + i * 256];  // 2048
    if (tid < HID) s_b2[tid] = b2[tid];
    if (tid < HID * 2) s_w3[tid] = w3[tid];
    if (tid < 2) s_b3[tid] = b3[tid];

    // stage x tile (+halo), clamped
    const float* xr = x + (size_t)row * N;
    for (int i = tid; i < BPT + WINDOW; i += 256) {
        int g = m0 + i;
        s_x[i] = (g < N) ? xr[g] : 0.0f;
    }
    __syncthreads();

    const int m = m0 + tid;
    if (m >= M) return;

    // ---- single-pass raw moments over the 50-window ----
    float S1 = 0.f, S2 = 0.f, S3 = 0.f, S4 = 0.f;
    #pragma unroll
    for (int i = 0; i < WINDOW; ++i) {
        float v  = s_x[tid + i];
        float v2 = v * v;
        S1 += v;
        S2 += v2;
        S3 = fmaf(v2, v,  S3);
        S4 = fmaf(v2, v2, S4);
    }
    const float invW = 1.0f / (float)WINDOW;
    float mean = S1 * invW;
    float mu2  = mean * mean;
    float c2 = S2 - (float)WINDOW * mu2;                                   // sum (x-mu)^2
    float c3 = S3 - 3.0f * mean * S2 + 2.0f * (float)WINDOW * mu2 * mean;  // sum (x-mu)^3
    float c4 = S4 - 4.0f * mean * S3 + 6.0f * mu2 * S2
                 - 3.0f * (float)WINDOW * mu2 * mu2;                       // sum (x-mu)^4
    float var     = c2 * (1.0f / (float)(WINDOW - 1));
    float sd      = sqrtf(var) + 1e-6f;
    float inv_sd  = 1.0f / sd;
    float inv_sd2 = inv_sd * inv_sd;
    float skew = c3 * invW * inv_sd2 * inv_sd;
    float kurt = c4 * invW * inv_sd2 * inv_sd2;

    // ---- MLP: 4 -> 64 -> 32 -> 2, h1 fused on the fly ----
    float h2[HID];
    #pragma unroll
    for (int k = 0; k < HID; ++k) h2[k] = s_b2[k];

    #pragma unroll 8
    for (int j = 0; j < H2X; ++j) {
        float h1 = s_b1[j];
        h1 = fmaf(mean, s_w1[j],           h1);
        h1 = fmaf(sd,   s_w1[H2X + j],     h1);
        h1 = fmaf(skew, s_w1[2 * H2X + j], h1);
        h1 = fmaf(kurt, s_w1[3 * H2X + j], h1);
        h1 = fmaxf(h1, 0.0f);
        const float4* w2r = (const float4*)(&s_w2[j * HID]);
        #pragma unroll
        for (int k4 = 0; k4 < HID / 4; ++k4) {
            float4 w = w2r[k4];
            h2[k4 * 4 + 0] = fmaf(h1, w.x, h2[k4 * 4 + 0]);
            h2[k4 * 4 + 1] = fmaf(h1, w.y, h2[k4 * 4 + 1]);
            h2[k4 * 4 + 2] = fmaf(h1, w.z, h2[k4 * 4 + 2]);
            h2[k4 * 4 + 3] = fmaf(h1, w.w, h2[k4 * 4 + 3]);
        }
    }

    float gam = s_b3[0], bet = s_b3[1];
    #pragma unroll
    for (int k = 0; k < HID; ++k) {
        float h = fmaxf(h2[k], 0.0f);
        gam = fmaf(h, s_w3[k * 2 + 0], gam);
        bet = fmaf(h, s_w3[k * 2 + 1], bet);
    }

    float center = s_x[tid + WINDOW / 2];
    out[(size_t)row * M + m] = fmaf((center - mean) * inv_sd, gam, bet);
}

extern "C" void kernel_launch(void* const* d_in, const int* in_sizes, int n_in,
                              void* d_out, int out_size, void* d_ws, size_t ws_size,
                              hipStream_t stream) {
    const float* x  = (const float*)d_in[0];
    const float* w1 = (const float*)d_in[1];
    const float* b1 = (const float*)d_in[2];
    const float* w2 = (const float*)d_in[3];
    const float* b2 = (const float*)d_in[4];
    const float* w3 = (const float*)d_in[5];
    const float* b3 = (const float*)d_in[6];
    float* out = (float*)d_out;

    const int N = 32768;
    const int B = in_sizes[0] / N;      // 32
    const int M = N - WINDOW + 1;       // 32719
    const int tiles = (M + BPT - 1) / BPT;  // 128

    dim3 grid(B * tiles), block(BPT);
    nsg_kernel<<<grid, block, 0, stream>>>(x, w1, b1, w2, b2, w3, b3,
                                           out, B, N, M, tiles);
}

// Round 2
// 32.677 us; speedup vs baseline: 2.4649x; 2.4649x over previous
//
#include <hip/hip_runtime.h>
#include <hip/hip_bf16.h>
#include <math.h>

#define WINDOW 50
#define BPT 256          // windows per block
#define HID 32
#define H2X 64

typedef __attribute__((ext_vector_type(8))) short short8;
typedef __attribute__((ext_vector_type(4))) float f32x4;
typedef unsigned int uint;

__device__ inline uint packbf(float a, float b) {
    __hip_bfloat162 t = __float22bfloat162_rn(float2{a, b});
    union { __hip_bfloat162 h; uint u; } cv; cv.h = t; return cv.u;
}

__global__ __launch_bounds__(256) void nsg_kernel(
    const float* __restrict__ x,
    const float* __restrict__ w1, const float* __restrict__ b1,
    const float* __restrict__ w2, const float* __restrict__ b2,
    const float* __restrict__ w3, const float* __restrict__ b3,
    float* __restrict__ out, int B, int N, int M, int tiles)
{
    __shared__ float s_x[BPT + WINDOW + 2];   // 308 floats
    __shared__ float s_b2[HID];               // per-lane indexed -> LDS
    __shared__ uint  s_bfrag[1024];           // w2 in B-frag order: [ks][nt][lane][4]
    __shared__ uint  s_awork[4][2048];        // per-wave: A-frags, then reused as h2T

    const int tid = threadIdx.x;
    const int wv  = tid >> 6;                 // wave id (0..3)
    const int wl  = tid & 63;                 // lane
    const int tile = blockIdx.x % tiles;
    const int row  = blockIdx.x / tiles;
    const int m0   = tile * BPT;

    // ---- stage x tile (+halo), clamped ----
    const float* xr = x + (size_t)row * N;
    for (int i = tid; i < BPT + WINDOW; i += 256) {
        int g = m0 + i;
        s_x[i] = (g < N) ? xr[g] : 0.0f;
    }
    if (tid < HID) s_b2[tid] = b2[tid];

    // ---- stage w2 into B-fragment order (bf16) ----
    // slot: ks = tid>>7, nt = (tid>>6)&1, lane l = tid&63
    {
        int ks = tid >> 7, nt = (tid >> 6) & 1, l = tid & 63;
        int n  = nt * 16 + (l & 15);
        int k0 = ks * 32 + (l >> 4) * 8;
        uint4 u;
        u.x = packbf(w2[(k0 + 0) * HID + n], w2[(k0 + 1) * HID + n]);
        u.y = packbf(w2[(k0 + 2) * HID + n], w2[(k0 + 3) * HID + n]);
        u.z = packbf(w2[(k0 + 4) * HID + n], w2[(k0 + 5) * HID + n]);
        u.w = packbf(w2[(k0 + 6) * HID + n], w2[(k0 + 7) * HID + n]);
        *(uint4*)&s_bfrag[((ks * 2 + nt) * 64 + l) * 4] = u;
    }
    __syncthreads();

    // ---- per-thread sliding-window moments ----
    float S1 = 0.f, S2 = 0.f, S3 = 0.f, S4 = 0.f;
    #pragma unroll
    for (int i = 0; i < WINDOW; ++i) {
        float v  = s_x[tid + i];
        float v2 = v * v;
        S1 += v;
        S2 += v2;
        S3 = fmaf(v2, v,  S3);
        S4 = fmaf(v2, v2, S4);
    }
    const float invW = 1.0f / (float)WINDOW;
    float mean = S1 * invW;
    float mu2  = mean * mean;
    float c2 = S2 - (float)WINDOW * mu2;
    float c3 = S3 - 3.0f * mean * S2 + 2.0f * (float)WINDOW * mu2 * mean;
    float c4 = S4 - 4.0f * mean * S3 + 6.0f * mu2 * S2
                 - 3.0f * (float)WINDOW * mu2 * mu2;
    float var     = c2 * (1.0f / (float)(WINDOW - 1));
    float sd      = sqrtf(var) + 1e-6f;
    float inv_sd  = 1.0f / sd;
    float inv_sd2 = inv_sd * inv_sd;
    float skew = c3 * invW * inv_sd2 * inv_sd;
    float kurt = c4 * invW * inv_sd2 * inv_sd2;
    float center = s_x[tid + WINDOW / 2];

    // ---- layer 1 (per-thread VALU), packed straight into A-fragment slots ----
    // A-frag layout (16x16x32): lane l holds A[m = l&15][k = (l>>4)*8 + e], e=0..7
    // thread (window) wl -> tile mt = wl>>4, tile-row rr = wl&15.
    // octet o (k = 8o..8o+7): ks = o>>2, lane-group g = o&3 -> lane g*16+rr.
    {
        const int mt = wl >> 4, rr = wl & 15;
        #pragma unroll
        for (int o = 0; o < 8; ++o) {
            float h[8];
            #pragma unroll
            for (int e = 0; e < 8; ++e) {
                int j = o * 8 + e;
                float v = b1[j];                      // uniform -> s_load
                v = fmaf(mean, w1[j],           v);
                v = fmaf(sd,   w1[64 + j],      v);
                v = fmaf(skew, w1[128 + j],     v);
                v = fmaf(kurt, w1[192 + j],     v);
                h[e] = fmaxf(v, 0.0f);
            }
            uint4 u;
            u.x = packbf(h[0], h[1]);
            u.y = packbf(h[2], h[3]);
            u.z = packbf(h[4], h[5]);
            u.w = packbf(h[6], h[7]);
            int ks = o >> 2, g = o & 3;
            int idx = (mt * 2 + ks) * 256 + (g * 16 + rr) * 4;
            *(uint4*)&s_awork[wv][idx] = u;
        }
    }
    __syncthreads();

    // ---- layer 2 via MFMA: per wave, 64x64 (A) @ 64x32 (B) ----
    const int lcol  = wl & 15;
    const int lrow4 = (wl >> 4) * 4;
    short8 bf00 = *(const short8*)&s_bfrag[((0 * 2 + 0) * 64 + wl) * 4];
    short8 bf01 = *(const short8*)&s_bfrag[((0 * 2 + 1) * 64 + wl) * 4];
    short8 bf10 = *(const short8*)&s_bfrag[((1 * 2 + 0) * 64 + wl) * 4];
    short8 bf11 = *(const short8*)&s_bfrag[((1 * 2 + 1) * 64 + wl) * 4];

    float bc0 = s_b2[lcol], bc1 = s_b2[16 + lcol];
    f32x4 acc[4][2];
    #pragma unroll
    for (int mt = 0; mt < 4; ++mt) {
        acc[mt][0] = f32x4{bc0, bc0, bc0, bc0};
        acc[mt][1] = f32x4{bc1, bc1, bc1, bc1};
    }
    #pragma unroll
    for (int mt = 0; mt < 4; ++mt) {
        short8 a0 = *(const short8*)&s_awork[wv][(mt * 2 + 0) * 256 + wl * 4];
        short8 a1 = *(const short8*)&s_awork[wv][(mt * 2 + 1) * 256 + wl * 4];
        acc[mt][0] = __builtin_amdgcn_mfma_f32_16x16x32_bf16(a0, bf00, acc[mt][0], 0, 0, 0);
        acc[mt][0] = __builtin_amdgcn_mfma_f32_16x16x32_bf16(a1, bf10, acc[mt][0], 0, 0, 0);
        acc[mt][1] = __builtin_amdgcn_mfma_f32_16x16x32_bf16(a0, bf01, acc[mt][1], 0, 0, 0);
        acc[mt][1] = __builtin_amdgcn_mfma_f32_16x16x32_bf16(a1, bf11, acc[mt][1], 0, 0, 0);
    }
    __syncthreads();   // all a-frag reads done before overwriting region with h2T

    // ---- write h2 col-major [col][row] (XOR-swizzled) into the same region ----
    #pragma unroll
    for (int mt = 0; mt < 4; ++mt) {
        #pragma unroll
        for (int nt = 0; nt < 2; ++nt) {
            int col  = nt * 16 + lcol;
            int row0 = mt * 16 + lrow4;
            int idx  = (col * 64 + row0) ^ ((col & 7) << 2);
            *(f32x4*)&s_awork[wv][idx] = acc[mt][nt];
        }
    }
    __syncthreads();

    // ---- layer 3 + reprojection (per-thread) ----
    float gam = b3[0], bet = b3[1];          // uniform -> s_load
    #pragma unroll
    for (int c = 0; c < HID; ++c) {
        int idx = (c * 64 + wl) ^ ((c & 7) << 2);
        float h = __uint_as_float(s_awork[wv][idx]);
        h = fmaxf(h, 0.0f);
        gam = fmaf(h, w3[c * 2 + 0], gam);   // uniform -> s_load
        bet = fmaf(h, w3[c * 2 + 1], bet);
    }

    const int m = m0 + tid;
    if (m < M)
        out[(size_t)row * M + m] = fmaf((center - mean) * inv_sd, gam, bet);
}

extern "C" void kernel_launch(void* const* d_in, const int* in_sizes, int n_in,
                              void* d_out, int out_size, void* d_ws, size_t ws_size,
                              hipStream_t stream) {
    const float* x  = (const float*)d_in[0];
    const float* w1 = (const float*)d_in[1];
    const float* b1 = (const float*)d_in[2];
    const float* w2 = (const float*)d_in[3];
    const float* b2 = (const float*)d_in[4];
    const float* w3 = (const float*)d_in[5];
    const float* b3 = (const float*)d_in[6];
    float* out = (float*)d_out;

    const int N = 32768;
    const int B = in_sizes[0] / N;           // 32
    const int M = N - WINDOW + 1;            // 32719
    const int tiles = (M + BPT - 1) / BPT;   // 128

    dim3 grid(B * tiles), block(BPT);
    nsg_kernel<<<grid, block, 0, stream>>>(x, w1, b1, w2, b2, w3, b3,
                                           out, B, N, M, tiles);
}